// Round 1
// baseline (438.234 us; speedup 1.0000x reference)
//
#include <hip/hip_runtime.h>

typedef __attribute__((ext_vector_type(8))) short bf16x8;
typedef __attribute__((ext_vector_type(4))) float f32x4;

__device__ __forceinline__ unsigned short f2bf(float f){
  unsigned u = __builtin_bit_cast(unsigned, f);
  u += 0x7fffu + ((u >> 16) & 1u);
  return (unsigned short)(u >> 16);
}

#define ASYNC16(ldsp, gp) __builtin_amdgcn_global_load_lds( \
    (const __attribute__((address_space(1))) unsigned int*)(gp), \
    (__attribute__((address_space(3))) unsigned int*)(ldsp), 16, 0, 0)

// ---- convert x (fp32 [b,56,56,384]) -> bf16 window-ordered [win*49+n][384] ----
__global__ __launch_bounds__(256) void convert_x_kernel(const float* __restrict__ x,
                                                        unsigned short* __restrict__ xb){
  int idx = blockIdx.x*256 + threadIdx.x;          // 100352*96 threads, 4 ch each
  int token = idx / 96, j = idx - token*96;
  int b = token / 3136, rem = token - b*3136;
  int rr = rem / 56, cp = rem - rr*56;
  int p = rr >> 3, h = rr & 7, q = cp >> 3, w = cp & 7;
  int orow = ((b*8 + h)*8 + w)*49 + p*7 + q;
  float4 v = *(const float4*)(x + (size_t)idx*4);
  ushort4 o;
  o.x = f2bf(v.x); o.y = f2bf(v.y); o.z = f2bf(v.z); o.w = f2bf(v.w);
  *(ushort4*)(xb + (size_t)orow*384 + j*4) = o;
}

// ---- convert weights fp32 -> bf16 ----
__global__ __launch_bounds__(256) void convert_w_kernel(const float* __restrict__ wq,
                                                        const float* __restrict__ wo,
                                                        unsigned short* __restrict__ wqb,
                                                        unsigned short* __restrict__ wob){
  int idx = blockIdx.x*256 + threadIdx.x;          // 147456 threads
  if (idx < 110592){
    float4 v = *(const float4*)(wq + (size_t)idx*4);
    ushort4 o; o.x=f2bf(v.x); o.y=f2bf(v.y); o.z=f2bf(v.z); o.w=f2bf(v.w);
    *(ushort4*)(wqb + (size_t)idx*4) = o;
  } else {
    int k = idx - 110592;
    float4 v = *(const float4*)(wo + (size_t)k*4);
    ushort4 o; o.x=f2bf(v.x); o.y=f2bf(v.y); o.z=f2bf(v.z); o.w=f2bf(v.w);
    *(ushort4*)(wob + (size_t)k*4) = o;
  }
}

// ---- 128x128 tile bf16 GEMM, C = A @ B^T + bias.  A:[M][K] bf16, B:[N][K] bf16.
// EPI 0: write q(*scale)/k/v bf16 [win][head][49][32].  EPI 1: write fp32 out un-windowed.
template<int EPI>
__global__ __launch_bounds__(256) void gemm128(const unsigned short* __restrict__ A,
                                               const unsigned short* __restrict__ B,
                                               const float* __restrict__ bias,
                                               int K,
                                               unsigned short* __restrict__ qo,
                                               unsigned short* __restrict__ ko,
                                               unsigned short* __restrict__ vo,
                                               float* __restrict__ out)
{
  __shared__ unsigned short Al[128*32];
  __shared__ unsigned short Bl[128*32];
  const int tid = threadIdx.x;
  const int lane = tid & 63, wid = tid >> 6;
  const int wr = wid >> 1, wc = wid & 1;
  const int l15 = lane & 15, kg = lane >> 4;

  const unsigned short* Ag = A + ((size_t)blockIdx.x*128 + (tid>>2))*K + (tid&3)*8;
  const unsigned short* Bg = B + ((size_t)blockIdx.y*128 + (tid>>2))*K + (tid&3)*8;
  unsigned short* Alw = Al + wid*512;   // wave-uniform LDS dest (1 KiB/wave/issue)
  unsigned short* Blw = Bl + wid*512;

  f32x4 acc[4][4] = {};

  for (int k0 = 0; k0 < K; k0 += 32){
    ASYNC16(Alw,        Ag + k0);
    ASYNC16(Alw + 2048, Ag + (size_t)64*K + k0);
    ASYNC16(Blw,        Bg + k0);
    ASYNC16(Blw + 2048, Bg + (size_t)64*K + k0);
    __syncthreads();
    bf16x8 af[4], bfv[4];
#pragma unroll
    for (int ti=0; ti<4; ++ti)
      af[ti] = *(const bf16x8*)(Al + (wr*64 + ti*16 + l15)*32 + kg*8);
#pragma unroll
    for (int tj=0; tj<4; ++tj)
      bfv[tj] = *(const bf16x8*)(Bl + (wc*64 + tj*16 + l15)*32 + kg*8);
#pragma unroll
    for (int ti=0; ti<4; ++ti)
#pragma unroll
      for (int tj=0; tj<4; ++tj)
        acc[ti][tj] = __builtin_amdgcn_mfma_f32_16x16x32_bf16(af[ti], bfv[tj], acc[ti][tj], 0,0,0);
    __syncthreads();
  }

  const int rbase = blockIdx.x*128 + wr*64 + kg*4;
  const int cbase = blockIdx.y*128 + wc*64 + l15;
#pragma unroll
  for (int ti=0; ti<4; ++ti){
#pragma unroll
    for (int tj=0; tj<4; ++tj){
      const int Cc = cbase + tj*16;
      const float bv = bias[Cc];
#pragma unroll
      for (int r=0; r<4; ++r){
        const int R = rbase + ti*16 + r;
        float val = acc[ti][tj][r] + bv;
        if (EPI == 0){
          int win = R / 49, nn = R - win*49;
          int t = Cc / 384, remc = Cc - t*384;
          int hd = remc >> 5, dd = remc & 31;
          size_t off = ((size_t)(win*12 + hd)*49 + nn)*32 + dd;
          if (t == 0)      qo[off] = f2bf(val * 0.17677669529663689f);
          else if (t == 1) ko[off] = f2bf(val);
          else             vo[off] = f2bf(val);
        } else {
          int win = R / 49, nn = R - win*49;
          int b = win >> 6, h = (win >> 3) & 7, w = win & 7;
          int p = nn / 7, q = nn - p*7;
          size_t tok = (size_t)b*3136 + (size_t)((p*8+h)*56 + (q*8+w));
          out[tok*384 + Cc] = val;
        }
      }
    }
  }
}

// ---- windowed attention: 1 wave per (window, head). 49 padded to 64. ----
__global__ __launch_bounds__(256) void attn_kernel(const unsigned short* __restrict__ q,
                                                   const unsigned short* __restrict__ k,
                                                   const unsigned short* __restrict__ v,
                                                   const float* __restrict__ rel_pos,
                                                   unsigned short* __restrict__ ao)
{
  __shared__ unsigned short P[4][4096];   // per-wave 64x64 bf16, XOR-swizzled
  const int tid = threadIdx.x, lane = tid & 63, wid = tid >> 6;
  const int l15 = lane & 15, kg = lane >> 4;
  const int win = blockIdx.x / 3;
  const int head = (blockIdx.x % 3)*4 + wid;
  const size_t base = ((size_t)win*12 + head)*1568;   // 49*32
  const unsigned short* qb = q + base;
  const unsigned short* kb = k + base;
  const unsigned short* vb = v + base;

  // S = q @ k^T  (rows/cols >=49 are garbage, masked below)
  f32x4 s[4][4] = {};
  {
    bf16x8 af[4], bfv[4];
#pragma unroll
    for (int ti=0; ti<4; ++ti) af[ti]  = *(const bf16x8*)(qb + (ti*16 + l15)*32 + kg*8);
#pragma unroll
    for (int tj=0; tj<4; ++tj) bfv[tj] = *(const bf16x8*)(kb + (tj*16 + l15)*32 + kg*8);
#pragma unroll
    for (int ti=0; ti<4; ++ti)
#pragma unroll
      for (int tj=0; tj<4; ++tj)
        s[ti][tj] = __builtin_amdgcn_mfma_f32_16x16x32_bf16(af[ti], bfv[tj], s[ti][tj], 0,0,0);
  }

  // bias + mask + wave-parallel softmax (rows live in 16-lane groups)
  const float* rp = rel_pos + head*169;
  float rinv[4][4];
#pragma unroll
  for (int ti=0; ti<4; ++ti){
#pragma unroll
    for (int r=0; r<4; ++r){
      int ii = ti*16 + kg*4 + r;
      int ic = ii < 49 ? ii : 48;
      int ip = ic / 7, iq = ic - ip*7;
      float m = -3e38f;
#pragma unroll
      for (int tj=0; tj<4; ++tj){
        int j = tj*16 + l15;
        float sv;
        if (j < 49){
          int jp = j / 7, jq = j - jp*7;
          sv = s[ti][tj][r] + rp[(ip-jp+6)*13 + (iq-jq+6)];
        } else sv = -3e38f;
        s[ti][tj][r] = sv;
        m = fmaxf(m, sv);
      }
#pragma unroll
      for (int d=1; d<16; d<<=1) m = fmaxf(m, __shfl_xor(m, d));
      float sum = 0.f;
#pragma unroll
      for (int tj=0; tj<4; ++tj){
        float e = __expf(s[ti][tj][r] - m);
        s[ti][tj][r] = e;
        sum += e;
      }
#pragma unroll
      for (int d=1; d<16; d<<=1) sum += __shfl_xor(sum, d);
      rinv[ti][r] = 1.0f / sum;
    }
  }

  // P -> LDS (bf16, XOR swizzle to kill row-major 128B-stride bank conflicts)
  unsigned short* Pl = P[wid];
#pragma unroll
  for (int ti=0; ti<4; ++ti)
#pragma unroll
    for (int tj=0; tj<4; ++tj)
#pragma unroll
      for (int r=0; r<4; ++r){
        int row = ti*16 + kg*4 + r, col = tj*16 + l15;
        unsigned boff = (unsigned)(row*128 + col*2);
        boff ^= (unsigned)((row & 7) << 4);
        *(unsigned short*)((char*)Pl + boff) = f2bf(s[ti][tj][r]);
      }
  __syncthreads();

  // O = P @ V   (P cols >=49 are exactly 0, so v-row garbage contributes 0)
  f32x4 o[4][2] = {};
#pragma unroll
  for (int ks=0; ks<2; ++ks){
    bf16x8 pa[4];
#pragma unroll
    for (int ti=0; ti<4; ++ti){
      int row = ti*16 + l15;
      unsigned boff = (unsigned)(row*128 + ks*64 + kg*16);
      boff ^= (unsigned)((row & 7) << 4);
      pa[ti] = *(const bf16x8*)((char*)Pl + boff);
    }
    bf16x8 vf[2];
#pragma unroll
    for (int tj=0; tj<2; ++tj){
#pragma unroll
      for (int e=0; e<8; ++e)
        vf[tj][e] = (short)vb[(ks*32 + kg*8 + e)*32 + tj*16 + l15];
    }
#pragma unroll
    for (int ti=0; ti<4; ++ti)
#pragma unroll
      for (int tj=0; tj<2; ++tj)
        o[ti][tj] = __builtin_amdgcn_mfma_f32_16x16x32_bf16(pa[ti], vf[tj], o[ti][tj], 0,0,0);
  }

  // store rows < 49, normalized, bf16 -> ao[win*49+n][head*32+dd]
#pragma unroll
  for (int ti=0; ti<4; ++ti)
#pragma unroll
    for (int r=0; r<4; ++r){
      int row = ti*16 + kg*4 + r;
      if (row < 49){
#pragma unroll
        for (int tj=0; tj<2; ++tj){
          int col = tj*16 + l15;
          float val = o[ti][tj][r] * rinv[ti][r];
          ao[((size_t)win*49 + row)*384 + head*32 + col] = f2bf(val);
        }
      }
    }
}

extern "C" void kernel_launch(void* const* d_in, const int* in_sizes, int n_in,
                              void* d_out, int out_size, void* d_ws, size_t ws_size,
                              hipStream_t stream)
{
  const float* x       = (const float*)d_in[0];   // 32*56*56*384
  const float* w_qkv   = (const float*)d_in[1];   // 1152*384
  const float* b_qkv   = (const float*)d_in[2];   // 1152
  const float* rel_pos = (const float*)d_in[3];   // 12*169
  const float* w_out   = (const float*)d_in[4];   // 384*384
  const float* b_out   = (const float*)d_in[5];   // 384
  float* out = (float*)d_out;                     // 100352*384

  char* ws = (char*)d_ws;
  unsigned short* wqb = (unsigned short*)ws;                        // 884736 B
  unsigned short* wob = (unsigned short*)(ws + 884736);             // 294912 B
  unsigned short* qws = (unsigned short*)(ws + 884736 + 294912);
  unsigned short* kws = qws + 38535168;
  unsigned short* vws = kws + 38535168;
  unsigned short* xb  = vws + 38535168;   // x_bf during GEMM1, attn-out after
  unsigned short* ao  = xb;

  convert_x_kernel<<<dim3(37632), dim3(256), 0, stream>>>(x, xb);
  convert_w_kernel<<<dim3(576),   dim3(256), 0, stream>>>(w_qkv, w_out, wqb, wob);
  gemm128<0><<<dim3(784, 9), dim3(256), 0, stream>>>(xb, wqb, b_qkv, 384, qws, kws, vws, nullptr);
  attn_kernel<<<dim3(6144), dim3(256), 0, stream>>>(qws, kws, vws, rel_pos, ao);
  gemm128<1><<<dim3(784, 3), dim3(256), 0, stream>>>(ao, wob, b_out, 384, nullptr, nullptr, nullptr, out);
}

// Round 2
// 409.206 us; speedup vs baseline: 1.0709x; 1.0709x over previous
//
#include <hip/hip_runtime.h>

typedef __attribute__((ext_vector_type(8))) short bf16x8;
typedef __attribute__((ext_vector_type(4))) float f32x4;

__device__ __forceinline__ unsigned short f2bf(float f){
  unsigned u = __builtin_bit_cast(unsigned, f);
  u += 0x7fffu + ((u >> 16) & 1u);
  return (unsigned short)(u >> 16);
}

#define ASYNC16(ldsp, gp) __builtin_amdgcn_global_load_lds( \
    (const __attribute__((address_space(1))) unsigned int*)(gp), \
    (__attribute__((address_space(3))) unsigned int*)(ldsp), 16, 0, 0)

// ---- convert x (fp32 [b,56,56,384]) -> bf16 window-ordered [win*49+n][384] ----
__global__ __launch_bounds__(256) void convert_x_kernel(const float* __restrict__ x,
                                                        unsigned short* __restrict__ xb){
  int idx = blockIdx.x*256 + threadIdx.x;          // 100352*96 threads, 4 ch each
  int token = idx / 96, j = idx - token*96;
  int b = token / 3136, rem = token - b*3136;
  int rr = rem / 56, cp = rem - rr*56;
  int p = rr >> 3, h = rr & 7, q = cp >> 3, w = cp & 7;
  int orow = ((b*8 + h)*8 + w)*49 + p*7 + q;
  float4 v = *(const float4*)(x + (size_t)idx*4);
  ushort4 o;
  o.x = f2bf(v.x); o.y = f2bf(v.y); o.z = f2bf(v.z); o.w = f2bf(v.w);
  *(ushort4*)(xb + (size_t)orow*384 + j*4) = o;
}

// ---- convert weights fp32 -> bf16 ----
__global__ __launch_bounds__(256) void convert_w_kernel(const float* __restrict__ wq,
                                                        const float* __restrict__ wo,
                                                        unsigned short* __restrict__ wqb,
                                                        unsigned short* __restrict__ wob){
  int idx = blockIdx.x*256 + threadIdx.x;          // 147456 threads
  if (idx < 110592){
    float4 v = *(const float4*)(wq + (size_t)idx*4);
    ushort4 o; o.x=f2bf(v.x); o.y=f2bf(v.y); o.z=f2bf(v.z); o.w=f2bf(v.w);
    *(ushort4*)(wqb + (size_t)idx*4) = o;
  } else {
    int k = idx - 110592;
    float4 v = *(const float4*)(wo + (size_t)k*4);
    ushort4 o; o.x=f2bf(v.x); o.y=f2bf(v.y); o.z=f2bf(v.z); o.w=f2bf(v.w);
    *(ushort4*)(wob + (size_t)k*4) = o;
  }
}

// ---- 128x128 tile bf16 GEMM, C = A @ B^T + bias, K=384 fixed.
// Depth-2 pipelined: counted vmcnt(4), raw barriers, dbuf LDS.
// EPI 0: write q(*scale)/k/v bf16 [win][head][49][32].  EPI 1: write fp32 out un-windowed.
template<int EPI>
__global__ __launch_bounds__(256) void gemm128(const unsigned short* __restrict__ A,
                                               const unsigned short* __restrict__ B,
                                               const float* __restrict__ bias,
                                               unsigned short* __restrict__ qo,
                                               unsigned short* __restrict__ ko,
                                               unsigned short* __restrict__ vo,
                                               float* __restrict__ out)
{
  constexpr int K = 384;
  constexpr int NT = 12;                    // K/32
  __shared__ unsigned short Al[2][128*32];
  __shared__ unsigned short Bl[2][128*32];
  const int tid = threadIdx.x;
  const int lane = tid & 63, wid = tid >> 6;
  const int wr = wid >> 1, wc = wid & 1;
  const int l15 = lane & 15, kg = lane >> 4;

  const unsigned short* Ag = A + ((size_t)blockIdx.x*128 + (tid>>2))*K + (tid&3)*8;
  const unsigned short* Bg = B + ((size_t)blockIdx.y*128 + (tid>>2))*K + (tid&3)*8;

  f32x4 acc[4][4] = {};

#define STAGE(buf, k0) do { \
    ASYNC16(&Al[buf][wid*512],        Ag + (k0)); \
    ASYNC16(&Al[buf][wid*512 + 2048], Ag + (size_t)64*K + (k0)); \
    ASYNC16(&Bl[buf][wid*512],        Bg + (k0)); \
    ASYNC16(&Bl[buf][wid*512 + 2048], Bg + (size_t)64*K + (k0)); \
  } while(0)

  STAGE(0, 0);
  STAGE(1, 32);

#pragma unroll
  for (int t = 0; t < NT; ++t){
    if (t == NT-1) asm volatile("s_waitcnt vmcnt(0)\n\ts_barrier" ::: "memory");
    else           asm volatile("s_waitcnt vmcnt(4)\n\ts_barrier" ::: "memory");

    const unsigned short* Ab = Al[t & 1];
    const unsigned short* Bb = Bl[t & 1];
    bf16x8 af[4], bfv[4];
#pragma unroll
    for (int ti=0; ti<4; ++ti)
      af[ti] = *(const bf16x8*)(Ab + (wr*64 + ti*16 + l15)*32 + kg*8);
#pragma unroll
    for (int tj=0; tj<4; ++tj)
      bfv[tj] = *(const bf16x8*)(Bb + (wc*64 + tj*16 + l15)*32 + kg*8);

    asm volatile("s_waitcnt lgkmcnt(0)\n\ts_barrier" ::: "memory");

    if (t < NT-2) STAGE(t & 1, (t+2)*32);   // refill the buffer just consumed

    __builtin_amdgcn_s_setprio(1);
#pragma unroll
    for (int ti=0; ti<4; ++ti)
#pragma unroll
      for (int tj=0; tj<4; ++tj)
        acc[ti][tj] = __builtin_amdgcn_mfma_f32_16x16x32_bf16(af[ti], bfv[tj], acc[ti][tj], 0,0,0);
    __builtin_amdgcn_s_setprio(0);
  }
#undef STAGE

  const int rbase = blockIdx.x*128 + wr*64 + kg*4;

  if (EPI == 0){
    const int by = blockIdx.y;
    const int t = by / 3;                          // block-uniform: q/k/v select
    unsigned short* __restrict__ Pout = (t==0) ? qo : ((t==1) ? ko : vo);
    const float scale = (t==0) ? 0.17677669529663689f : 1.0f;
    const int cb = (by - t*3)*128 + wc*64;         // col base within 384
    int hoff[4]; float bvs[4];
#pragma unroll
    for (int tj=0; tj<4; ++tj){
      int colt = cb + tj*16;
      hoff[tj] = (colt>>5)*1568 + (colt&31) + l15; // head*49*32 + dd
      bvs[tj] = bias[by*128 + wc*64 + tj*16 + l15] * scale;
    }
#pragma unroll
    for (int ti=0; ti<4; ++ti){
#pragma unroll
      for (int r=0; r<4; ++r){
        int R = rbase + ti*16 + r;
        int win = R / 49, nn = R - win*49;
        size_t rowoff = (size_t)win*18816 + nn*32;
#pragma unroll
        for (int tj=0; tj<4; ++tj)
          Pout[rowoff + hoff[tj]] = f2bf(acc[ti][tj][r]*scale + bvs[tj]);
      }
    }
  } else {
    const int cbs = blockIdx.y*128 + wc*64;        // scalar col base
    float bv[4];
#pragma unroll
    for (int tj=0; tj<4; ++tj) bv[tj] = bias[cbs + tj*16 + l15];
#pragma unroll
    for (int ti=0; ti<4; ++ti){
#pragma unroll
      for (int r=0; r<4; ++r){
        int R = rbase + ti*16 + r;
        int win = R / 49, nn = R - win*49;
        int p = nn / 7, q = nn - p*7;
        int h = (win >> 3) & 7, w = win & 7;
        size_t tok = (size_t)(win >> 6)*3136 + (size_t)((p*8 + h)*56 + q*8 + w);
        float* __restrict__ orow = out + tok*384 + cbs + l15;
#pragma unroll
        for (int tj=0; tj<4; ++tj)
          orow[tj*16] = acc[ti][tj][r] + bv[tj];
      }
    }
  }
}

// ---- windowed attention: 1 wave per (window, head). 49 padded to 64. ----
__global__ __launch_bounds__(256) void attn_kernel(const unsigned short* __restrict__ q,
                                                   const unsigned short* __restrict__ k,
                                                   const unsigned short* __restrict__ v,
                                                   const float* __restrict__ rel_pos,
                                                   unsigned short* __restrict__ ao)
{
  __shared__ unsigned short P[4][4096];   // per-wave 64x64 bf16, XOR-swizzled
  const int tid = threadIdx.x, lane = tid & 63, wid = tid >> 6;
  const int l15 = lane & 15, kg = lane >> 4;
  const int win = blockIdx.x / 3;
  const int head = (blockIdx.x % 3)*4 + wid;
  const size_t base = ((size_t)win*12 + head)*1568;   // 49*32
  const unsigned short* qb = q + base;
  const unsigned short* kb = k + base;
  const unsigned short* vb = v + base;

  // S = q @ k^T  (rows/cols >=49 are garbage, masked below)
  f32x4 s[4][4] = {};
  {
    bf16x8 af[4], bfv[4];
#pragma unroll
    for (int ti=0; ti<4; ++ti) af[ti]  = *(const bf16x8*)(qb + (ti*16 + l15)*32 + kg*8);
#pragma unroll
    for (int tj=0; tj<4; ++tj) bfv[tj] = *(const bf16x8*)(kb + (tj*16 + l15)*32 + kg*8);
    __builtin_amdgcn_s_setprio(1);
#pragma unroll
    for (int ti=0; ti<4; ++ti)
#pragma unroll
      for (int tj=0; tj<4; ++tj)
        s[ti][tj] = __builtin_amdgcn_mfma_f32_16x16x32_bf16(af[ti], bfv[tj], s[ti][tj], 0,0,0);
    __builtin_amdgcn_s_setprio(0);
  }

  // bias + mask + wave-parallel softmax (rows live in 16-lane groups)
  const float* rp = rel_pos + head*169;
  float rinv[4][4];
#pragma unroll
  for (int ti=0; ti<4; ++ti){
#pragma unroll
    for (int r=0; r<4; ++r){
      int ii = ti*16 + kg*4 + r;
      int ic = ii < 49 ? ii : 48;
      int ip = ic / 7, iq = ic - ip*7;
      float m = -3e38f;
#pragma unroll
      for (int tj=0; tj<4; ++tj){
        int j = tj*16 + l15;
        float sv;
        if (j < 49){
          int jp = j / 7, jq = j - jp*7;
          sv = s[ti][tj][r] + rp[(ip-jp+6)*13 + (iq-jq+6)];
        } else sv = -3e38f;
        s[ti][tj][r] = sv;
        m = fmaxf(m, sv);
      }
#pragma unroll
      for (int d=1; d<16; d<<=1) m = fmaxf(m, __shfl_xor(m, d));
      float sum = 0.f;
#pragma unroll
      for (int tj=0; tj<4; ++tj){
        float e = __expf(s[ti][tj][r] - m);
        s[ti][tj][r] = e;
        sum += e;
      }
#pragma unroll
      for (int d=1; d<16; d<<=1) sum += __shfl_xor(sum, d);
      rinv[ti][r] = 1.0f / sum;
    }
  }

  // P -> LDS (bf16, XOR swizzle); P is wave-private so no __syncthreads needed
  unsigned short* Pl = P[wid];
#pragma unroll
  for (int ti=0; ti<4; ++ti)
#pragma unroll
    for (int tj=0; tj<4; ++tj)
#pragma unroll
      for (int r=0; r<4; ++r){
        int row = ti*16 + kg*4 + r, col = tj*16 + l15;
        unsigned boff = (unsigned)(row*128 + col*2);
        boff ^= (unsigned)((row & 7) << 4);
        *(unsigned short*)((char*)Pl + boff) = f2bf(s[ti][tj][r]);
      }

  // O = P @ V   (P cols >=49 are exactly 0, so v-row garbage contributes 0)
  f32x4 o[4][2] = {};
#pragma unroll
  for (int ks=0; ks<2; ++ks){
    bf16x8 pa[4];
#pragma unroll
    for (int ti=0; ti<4; ++ti){
      int row = ti*16 + l15;
      unsigned boff = (unsigned)(row*128 + ks*64 + kg*16);
      boff ^= (unsigned)((row & 7) << 4);
      pa[ti] = *(const bf16x8*)((char*)Pl + boff);
    }
    bf16x8 vf[2];
#pragma unroll
    for (int tj=0; tj<2; ++tj){
#pragma unroll
      for (int e=0; e<8; ++e)
        vf[tj][e] = (short)vb[(ks*32 + kg*8 + e)*32 + tj*16 + l15];
    }
    __builtin_amdgcn_s_setprio(1);
#pragma unroll
    for (int ti=0; ti<4; ++ti)
#pragma unroll
      for (int tj=0; tj<2; ++tj)
        o[ti][tj] = __builtin_amdgcn_mfma_f32_16x16x32_bf16(pa[ti], vf[tj], o[ti][tj], 0,0,0);
    __builtin_amdgcn_s_setprio(0);
  }

  // store rows < 49, normalized, bf16 -> ao[win*49+n][head*32+dd]
#pragma unroll
  for (int ti=0; ti<4; ++ti)
#pragma unroll
    for (int r=0; r<4; ++r){
      int row = ti*16 + kg*4 + r;
      if (row < 49){
#pragma unroll
        for (int tj=0; tj<2; ++tj){
          int col = tj*16 + l15;
          float val = o[ti][tj][r] * rinv[ti][r];
          ao[((size_t)win*49 + row)*384 + head*32 + col] = f2bf(val);
        }
      }
    }
}

extern "C" void kernel_launch(void* const* d_in, const int* in_sizes, int n_in,
                              void* d_out, int out_size, void* d_ws, size_t ws_size,
                              hipStream_t stream)
{
  const float* x       = (const float*)d_in[0];   // 32*56*56*384
  const float* w_qkv   = (const float*)d_in[1];   // 1152*384
  const float* b_qkv   = (const float*)d_in[2];   // 1152
  const float* rel_pos = (const float*)d_in[3];   // 12*169
  const float* w_out   = (const float*)d_in[4];   // 384*384
  const float* b_out   = (const float*)d_in[5];   // 384
  float* out = (float*)d_out;                     // 100352*384

  char* ws = (char*)d_ws;
  unsigned short* wqb = (unsigned short*)ws;                        // 884736 B
  unsigned short* wob = (unsigned short*)(ws + 884736);             // 294912 B
  unsigned short* qws = (unsigned short*)(ws + 884736 + 294912);
  unsigned short* kws = qws + 38535168;
  unsigned short* vws = kws + 38535168;
  unsigned short* xb  = vws + 38535168;   // x_bf during GEMM1, attn-out after
  unsigned short* ao  = xb;

  convert_x_kernel<<<dim3(37632), dim3(256), 0, stream>>>(x, xb);
  convert_w_kernel<<<dim3(576),   dim3(256), 0, stream>>>(w_qkv, w_out, wqb, wob);
  gemm128<0><<<dim3(784, 9), dim3(256), 0, stream>>>(xb, wqb, b_qkv, qws, kws, vws, nullptr);
  attn_kernel<<<dim3(6144), dim3(256), 0, stream>>>(qws, kws, vws, rel_pos, ao);
  gemm128<1><<<dim3(784, 3), dim3(256), 0, stream>>>(ao, wob, b_out, nullptr, nullptr, nullptr, out);
}